// Round 1
// baseline (19.773 us; speedup 1.0000x reference)
//
#include <hip/hip_runtime.h>
#include <float.h>

#define INF_VAL 100000000.0f
#define NUM_CLASSES_K 80

// One thread per (image b, location l). Each block stages image b's boxes
// into LDS: x1,y1,x2,y2,area (float) + class (int) per box.
__global__ void fcos_targets_kernel(const float* __restrict__ locations,
                                    const float* __restrict__ size_ranges,
                                    const float* __restrict__ strides,
                                    const float* __restrict__ bboxes,
                                    const int* __restrict__ classes,
                                    float* __restrict__ out_labels,
                                    float* __restrict__ out_reg,
                                    int L, int M) {
    const int b = blockIdx.y;
    const int l = blockIdx.x * blockDim.x + threadIdx.x;

    extern __shared__ float smem[];
    float* sx1   = smem;
    float* sy1   = smem + M;
    float* sx2   = smem + 2 * M;
    float* sy2   = smem + 3 * M;
    float* sarea = smem + 4 * M;
    int*   scls  = (int*)(smem + 5 * M);

    for (int m = threadIdx.x; m < M; m += blockDim.x) {
        const float x1 = bboxes[(size_t)((b * M + m) * 4) + 0];
        const float y1 = bboxes[(size_t)((b * M + m) * 4) + 1];
        const float x2 = bboxes[(size_t)((b * M + m) * 4) + 2];
        const float y2 = bboxes[(size_t)((b * M + m) * 4) + 3];
        sx1[m] = x1;
        sy1[m] = y1;
        sx2[m] = x2;
        sy2[m] = y2;
        sarea[m] = (x2 - x1) * (y2 - y1);
        scls[m] = classes[b * M + m];
    }
    __syncthreads();

    if (l >= L) return;

    const float xs = locations[(size_t)l * 2 + 0];
    const float ys = locations[(size_t)l * 2 + 1];
    const float lo = size_ranges[(size_t)l * 2 + 0];
    const float hi = size_ranges[(size_t)l * 2 + 1];

    // Emulate jnp.argmin (first occurrence of min) over loc_to_area.
    float best = FLT_MAX;
    int best_m = 0;
    for (int m = 0; m < M; ++m) {
        const float dl = xs - sx1[m];
        const float dt = ys - sy1[m];
        const float dr = sx2[m] - xs;
        const float db = sy2[m] - ys;
        const float mn = fminf(fminf(dl, dt), fminf(dr, db));
        const float mx = fmaxf(fmaxf(dl, dt), fmaxf(dr, db));
        const bool in_box = mn > 0.0f;
        const bool cared = (mx >= lo) && (mx <= hi);
        const float cost = (in_box && cared) ? sarea[m] : INF_VAL;
        if (cost < best) {  // strict <  => first-occurrence argmin
            best = cost;
            best_m = m;
        }
    }

    // Recompute reg for the winning box (matches reference reg[l, inds]).
    const float inv_valid = 1.0f;  // reference divides by stride regardless
    (void)inv_valid;
    const float stride = strides[l];
    const float dl = (xs - sx1[best_m]) / stride;
    const float dt = (ys - sy1[best_m]) / stride;
    const float dr = (sx2[best_m] - xs) / stride;
    const float db = (sy2[best_m] - ys) / stride;

    const int label = (best >= INF_VAL) ? NUM_CLASSES_K : scls[best_m];

    out_labels[(size_t)b * L + l] = (float)label;
    const size_t base = ((size_t)b * L + l) * 4;
    out_reg[base + 0] = dl;
    out_reg[base + 1] = dt;
    out_reg[base + 2] = dr;
    out_reg[base + 3] = db;
}

extern "C" void kernel_launch(void* const* d_in, const int* in_sizes, int n_in,
                              void* d_out, int out_size, void* d_ws, size_t ws_size,
                              hipStream_t stream) {
    const float* locations   = (const float*)d_in[0];
    const float* size_ranges = (const float*)d_in[1];
    const float* strides     = (const float*)d_in[2];
    const float* bboxes      = (const float*)d_in[3];
    const int*   classes     = (const int*)d_in[4];

    const int L  = in_sizes[2];          // strides_per_loc: (L,)
    const int BM = in_sizes[4];          // gt_classes: (B, M)
    const int B  = out_size / (5 * L);   // out = B*L labels + B*L*4 reg
    const int M  = BM / B;

    float* out        = (float*)d_out;
    float* out_labels = out;                      // first B*L elements
    float* out_reg    = out + (size_t)B * L;      // then B*L*4

    dim3 block(256);
    dim3 grid((L + 255) / 256, B);
    const size_t shmem = (size_t)M * 6 * sizeof(float);

    hipLaunchKernelGGL(fcos_targets_kernel, grid, block, shmem, stream,
                       locations, size_ranges, strides, bboxes, classes,
                       out_labels, out_reg, L, M);
}

// Round 2
// 18.100 us; speedup vs baseline: 1.0924x; 1.0924x over previous
//
#include <hip/hip_runtime.h>
#include <float.h>

#define INF_VAL 100000000.0f
#define NUM_CLASSES_K 80

// One thread per (image b, location l). Box data is wave-uniform in the
// m-loop, so it's read straight from global with uniform addressing ->
// compiler emits s_load_dwordx4 (scalar cache), keeping LDS and the vector
// memory pipe idle. VALU does ~17 ops/iteration.
__global__ void fcos_targets_kernel(const float2* __restrict__ locations,
                                    const float2* __restrict__ size_ranges,
                                    const float* __restrict__ strides,
                                    const float4* __restrict__ bboxes,
                                    const int* __restrict__ classes,
                                    float* __restrict__ out_labels,
                                    float4* __restrict__ out_reg,
                                    int L, int M) {
    const int b = blockIdx.y;
    const int l = blockIdx.x * blockDim.x + threadIdx.x;
    if (l >= L) return;

    const float2 loc = locations[l];
    const float2 sr  = size_ranges[l];
    const float xs = loc.x, ys = loc.y;
    const float lo = sr.x,  hi = sr.y;

    const float4* boxes_b = bboxes + (size_t)b * M;

    // jnp.argmin first-occurrence semantics via strict <, best init FLT_MAX
    // (all-INF rows settle on index 0 after the first iteration).
    float best  = FLT_MAX;
    int  best_m = 0;
#pragma unroll 4
    for (int m = 0; m < M; ++m) {
        const float4 bx = boxes_b[m];          // uniform -> s_load_dwordx4
        const float dl = xs - bx.x;
        const float dt = ys - bx.y;
        const float dr = bx.z - xs;
        const float db = bx.w - ys;
        const float mn = fminf(fminf(dl, dt), fminf(dr, db));
        const float mx = fmaxf(fmaxf(dl, dt), fmaxf(dr, db));
        // exact same fp expression as reference: (x2-x1)*(y2-y1)
        const float area = (bx.z - bx.x) * (bx.w - bx.y);
        const bool ok = (mn > 0.0f) && (mx >= lo) && (mx <= hi);
        const float cost = ok ? area : INF_VAL;
        const bool better = cost < best;       // strict < => first occurrence
        best   = better ? cost : best;
        best_m = better ? m : best_m;
    }

    // Winner-only fetches (divergent index, executed once).
    const float4 wb = boxes_b[best_m];
    const int    wc = classes[b * M + best_m];
    const float  stride = strides[l];

    const int label = (best >= INF_VAL) ? NUM_CLASSES_K : wc;

    float4 reg;
    reg.x = (xs - wb.x) / stride;
    reg.y = (ys - wb.y) / stride;
    reg.z = (wb.z - xs) / stride;
    reg.w = (wb.w - ys) / stride;

    out_labels[(size_t)b * L + l] = (float)label;
    out_reg[(size_t)b * L + l]    = reg;
}

extern "C" void kernel_launch(void* const* d_in, const int* in_sizes, int n_in,
                              void* d_out, int out_size, void* d_ws, size_t ws_size,
                              hipStream_t stream) {
    const float2* locations   = (const float2*)d_in[0];
    const float2* size_ranges = (const float2*)d_in[1];
    const float*  strides     = (const float*)d_in[2];
    const float4* bboxes      = (const float4*)d_in[3];
    const int*    classes     = (const int*)d_in[4];

    const int L  = in_sizes[2];          // strides_per_loc: (L,)
    const int BM = in_sizes[4];          // gt_classes: (B, M)
    const int B  = out_size / (5 * L);   // out = B*L labels + B*L*4 reg
    const int M  = BM / B;

    float*  out        = (float*)d_out;
    float*  out_labels = out;                          // first B*L
    float4* out_reg    = (float4*)(out + (size_t)B * L); // then B*L*4 (16B aligned)

    dim3 block(256);
    dim3 grid((L + 255) / 256, B);

    hipLaunchKernelGGL(fcos_targets_kernel, grid, block, 0, stream,
                       locations, size_ranges, strides, bboxes, classes,
                       out_labels, out_reg, L, M);
}